// Round 7
// baseline (52.347 us; speedup 1.0000x reference)
//
#include <hip/hip_runtime.h>
#include <hip/hip_bf16.h>
#include <math.h>

// Problem constants: B=32768, S=16, D=64
#define Bn 32768
#define Sn 16
#define Dn 64
#define THREADS 256
#define WPB 4            // waves per block; TWO batches per wave

typedef __attribute__((ext_vector_type(8))) short bf16x8;   // 8 bf16 (4 VGPRs)
typedef __attribute__((ext_vector_type(4))) float f32x4;

static __device__ inline unsigned short f2bf(float f) {
    __hip_bfloat16 h = __float2bfloat16(f);                 // RN
    return *reinterpret_cast<unsigned short*>(&h);
}
static __device__ inline float bf2f(unsigned short u) {     // exact
    union { unsigned int i; float f; } v;
    v.i = ((unsigned int)u) << 16;
    return v.f;
}

// convert 8 consecutive f32 -> bf16x8 fragment, accumulating sum of squares
// of the ROUNDED values into s (so d2 = ||x~||^2+||y~||^2-2<x~,y~> >= 0).
static __device__ inline bf16x8 cvt_frag(float4 lo, float4 hi, float& s) {
    bf16x8 r;
    const float* pl = &lo.x;
    const float* ph = &hi.x;
    #pragma unroll
    for (int j = 0; j < 4; ++j) {
        unsigned short u = f2bf(pl[j]);
        float f = bf2f(u);
        s = fmaf(f, f, s);
        r[j] = (short)u;
    }
    #pragma unroll
    for (int j = 0; j < 4; ++j) {
        unsigned short u = f2bf(ph[j]);
        float f = bf2f(u);
        s = fmaf(f, f, s);
        r[4 + j] = (short)u;
    }
    return r;
}

__global__ __launch_bounds__(THREADS, 4)
void get_logit_mc_kernel(const float* __restrict__ z1,
                         const float* __restrict__ z2,
                         const float* __restrict__ pa,
                         const float* __restrict__ pb,
                         float* __restrict__ out) {
    const int t     = threadIdx.x;
    const int wave  = t >> 6;
    const int lane  = t & 63;
    const int wid   = blockIdx.x * WPB + wave;   // global wave id
    const int bat0  = wid * 2;                   // two batches per wave
    const int bat1  = bat0 + 1;
    const int m     = lane & 15;   // A row / B col index
    const int g     = lane >> 4;   // k-group

    const float* p1a = z1 + ((size_t)bat0 << 10) + (m << 6);
    const float* p2a = z2 + ((size_t)bat0 << 10) + (m << 6);
    const float* p1b = z1 + ((size_t)bat1 << 10) + (m << 6);
    const float* p2b = z2 + ((size_t)bat1 << 10) + (m << 6);

    // ---- issue ALL 16 loads before any dependent compute (max MLP) ----
    float4 a0 = *reinterpret_cast<const float4*>(p1a + g * 8);
    float4 a1 = *reinterpret_cast<const float4*>(p1a + g * 8 + 4);
    float4 a2 = *reinterpret_cast<const float4*>(p1a + 32 + g * 8);
    float4 a3 = *reinterpret_cast<const float4*>(p1a + 32 + g * 8 + 4);
    float4 b0 = *reinterpret_cast<const float4*>(p2a + g * 8);
    float4 b1 = *reinterpret_cast<const float4*>(p2a + g * 8 + 4);
    float4 b2 = *reinterpret_cast<const float4*>(p2a + 32 + g * 8);
    float4 b3 = *reinterpret_cast<const float4*>(p2a + 32 + g * 8 + 4);
    float4 c0 = *reinterpret_cast<const float4*>(p1b + g * 8);
    float4 c1 = *reinterpret_cast<const float4*>(p1b + g * 8 + 4);
    float4 c2 = *reinterpret_cast<const float4*>(p1b + 32 + g * 8);
    float4 c3 = *reinterpret_cast<const float4*>(p1b + 32 + g * 8 + 4);
    float4 e0 = *reinterpret_cast<const float4*>(p2b + g * 8);
    float4 e1 = *reinterpret_cast<const float4*>(p2b + g * 8 + 4);
    float4 e2 = *reinterpret_cast<const float4*>(p2b + 32 + g * 8);
    float4 e3 = *reinterpret_cast<const float4*>(p2b + 32 + g * 8 + 4);

    const float av = pa[0];
    const float bv = pb[0];

    // ---- batch 0 ----
    float s1a = 0.0f, s2a = 0.0f;
    bf16x8 fa0 = cvt_frag(a0, a1, s1a);
    bf16x8 fa1 = cvt_frag(a2, a3, s1a);
    bf16x8 fb0 = cvt_frag(b0, b1, s2a);
    bf16x8 fb1 = cvt_frag(b2, b3, s2a);
    f32x4 accA = {0.f, 0.f, 0.f, 0.f};
    accA = __builtin_amdgcn_mfma_f32_16x16x32_bf16(fa0, fb0, accA, 0, 0, 0);
    accA = __builtin_amdgcn_mfma_f32_16x16x32_bf16(fa1, fb1, accA, 0, 0, 0);

    // ---- batch 1 ----
    float s1b = 0.0f, s2b = 0.0f;
    bf16x8 fc0 = cvt_frag(c0, c1, s1b);
    bf16x8 fc1 = cvt_frag(c2, c3, s1b);
    bf16x8 fe0 = cvt_frag(e0, e1, s2b);
    bf16x8 fe1 = cvt_frag(e2, e3, s2b);
    f32x4 accB = {0.f, 0.f, 0.f, 0.f};
    accB = __builtin_amdgcn_mfma_f32_16x16x32_bf16(fc0, fe0, accB, 0, 0, 0);
    accB = __builtin_amdgcn_mfma_f32_16x16x32_bf16(fc1, fe1, accB, 0, 0, 0);

    // ---- row-norm reduces (lanes m, m+16, m+32, m+48 hold disjoint k) ----
    s1a += __shfl_xor(s1a, 16);  s1a += __shfl_xor(s1a, 32);
    s2a += __shfl_xor(s2a, 16);  s2a += __shfl_xor(s2a, 32);
    s1b += __shfl_xor(s1b, 16);  s1b += __shfl_xor(s1b, 32);
    s2b += __shfl_xor(s2b, 16);  s2b += __shfl_xor(s2b, 32);

    // ---- epilogue: C/D layout acc[j] -> row=g*4+j, col=m ----
    float* poA = out + ((size_t)bat0 << 8);
    float* poB = out + ((size_t)bat1 << 8);
    #pragma unroll
    for (int j = 0; j < 4; ++j) {
        int   row = g * 4 + j;
        float s1r = __shfl(s1a, row);
        float d2  = fmaxf(s1r + s2a - 2.0f * accA[j], 0.0f);
        float x   = fmaf(sqrtf(d2), av, bv);
        float sg  = 1.0f / (1.0f + __expf(-x));
        sg = fminf(sg, 1.0f);
        sg = fmaxf(sg, 1e-8f);
        poA[row * 16 + m] = sg;

        float s1s = __shfl(s1b, row);
        float e2v = fmaxf(s1s + s2b - 2.0f * accB[j], 0.0f);
        float xb  = fmaf(sqrtf(e2v), av, bv);
        float sb  = 1.0f / (1.0f + __expf(-xb));
        sb = fminf(sb, 1.0f);
        sb = fmaxf(sb, 1e-8f);
        poB[row * 16 + m] = sb;
    }
}

extern "C" void kernel_launch(void* const* d_in, const int* in_sizes, int n_in,
                              void* d_out, int out_size, void* d_ws, size_t ws_size,
                              hipStream_t stream) {
    const float* z1 = (const float*)d_in[0];
    const float* z2 = (const float*)d_in[1];
    const float* pa = (const float*)d_in[2];
    const float* pb = (const float*)d_in[3];
    float* out      = (float*)d_out;

    dim3 grid(Bn / (2 * WPB));   // 4096 blocks
    dim3 block(THREADS);
    hipLaunchKernelGGL(get_logit_mc_kernel, grid, block, 0, stream,
                       z1, z2, pa, pb, out);
}

// Round 8
// 49.555 us; speedup vs baseline: 1.0564x; 1.0564x over previous
//
#include <hip/hip_runtime.h>
#include <hip/hip_bf16.h>
#include <math.h>

// Problem constants: B=32768, S=16, D=64
// Roofline note: 268 MB compulsory reads + 33.6 MB writes at the ~6.3 TB/s
// blended HBM+L3 ceiling = ~48 us floor; this kernel measures ~50 us (96%).
#define Bn 32768
#define Sn 16
#define Dn 64
#define THREADS 256
#define WPB 4            // waves per block; one batch per wave

typedef __attribute__((ext_vector_type(8))) short bf16x8;   // 8 bf16 (4 VGPRs)
typedef __attribute__((ext_vector_type(4))) float f32x4;

static __device__ inline unsigned short f2bf(float f) {
    __hip_bfloat16 h = __float2bfloat16(f);                 // RN
    return *reinterpret_cast<unsigned short*>(&h);
}
static __device__ inline float bf2f(unsigned short u) {     // exact
    union { unsigned int i; float f; } v;
    v.i = ((unsigned int)u) << 16;
    return v.f;
}

// convert 8 consecutive f32 -> bf16x8 fragment, accumulating sum of squares
// of the ROUNDED values into s (so d2 = ||x~||^2+||y~||^2-2<x~,y~> >= 0).
static __device__ inline bf16x8 cvt_frag(float4 lo, float4 hi, float& s) {
    bf16x8 r;
    const float* pl = &lo.x;
    const float* ph = &hi.x;
    #pragma unroll
    for (int j = 0; j < 4; ++j) {
        unsigned short u = f2bf(pl[j]);
        float f = bf2f(u);
        s = fmaf(f, f, s);
        r[j] = (short)u;
    }
    #pragma unroll
    for (int j = 0; j < 4; ++j) {
        unsigned short u = f2bf(ph[j]);
        float f = bf2f(u);
        s = fmaf(f, f, s);
        r[4 + j] = (short)u;
    }
    return r;
}

__global__ __launch_bounds__(THREADS, 4)
void get_logit_mc_kernel(const float* __restrict__ z1,
                         const float* __restrict__ z2,
                         const float* __restrict__ pa,
                         const float* __restrict__ pb,
                         float* __restrict__ out) {
    const int t     = threadIdx.x;
    const int wave  = t >> 6;
    const int lane  = t & 63;
    const int batch = blockIdx.x * WPB + wave;
    const int m     = lane & 15;   // A row / B col index
    const int g     = lane >> 4;   // k-group (8 k's per group per mfma)

    // Fragment loads: lane covers z[batch][m][k], k in [8g,8g+8) and [32+8g,...)
    // Union over the wave = the full contiguous 4KB tile of each input.
    const float* p1 = z1 + ((size_t)batch << 10) + (m << 6);
    const float* p2 = z2 + ((size_t)batch << 10) + (m << 6);

    float4 a0 = *reinterpret_cast<const float4*>(p1 + g * 8);
    float4 a1 = *reinterpret_cast<const float4*>(p1 + g * 8 + 4);
    float4 a2 = *reinterpret_cast<const float4*>(p1 + 32 + g * 8);
    float4 a3 = *reinterpret_cast<const float4*>(p1 + 32 + g * 8 + 4);
    float4 b0 = *reinterpret_cast<const float4*>(p2 + g * 8);
    float4 b1 = *reinterpret_cast<const float4*>(p2 + g * 8 + 4);
    float4 b2 = *reinterpret_cast<const float4*>(p2 + 32 + g * 8);
    float4 b3 = *reinterpret_cast<const float4*>(p2 + 32 + g * 8 + 4);

    float s1 = 0.0f, s2 = 0.0f;
    bf16x8 fa0 = cvt_frag(a0, a1, s1);
    bf16x8 fa1 = cvt_frag(a2, a3, s1);
    bf16x8 fb0 = cvt_frag(b0, b1, s2);
    bf16x8 fb1 = cvt_frag(b2, b3, s2);

    // dots[m][n] = z1[m] . z2[n]  via 2 K-steps of 16x16x32 bf16 MFMA
    f32x4 acc = {0.f, 0.f, 0.f, 0.f};
    acc = __builtin_amdgcn_mfma_f32_16x16x32_bf16(fa0, fb0, acc, 0, 0, 0);
    acc = __builtin_amdgcn_mfma_f32_16x16x32_bf16(fa1, fb1, acc, 0, 0, 0);

    // Row-norm reduce: lanes {m, m+16, m+32, m+48} hold disjoint k-ranges.
    s1 += __shfl_xor(s1, 16);
    s1 += __shfl_xor(s1, 32);
    s2 += __shfl_xor(s2, 16);
    s2 += __shfl_xor(s2, 32);
    // now: s1 = ||z1~[m]||^2 in every lane with (lane&15)==m; same for s2.

    const float av = pa[0];
    const float bv = pb[0];

    // C/D layout (m89): acc[j] at lane l -> row=(l>>4)*4+j, col=l&15
    float* po = out + ((size_t)batch << 8);
    #pragma unroll
    for (int j = 0; j < 4; ++j) {
        int   row = g * 4 + j;
        float s1r = __shfl(s1, row);            // ||z1~[row]||^2 from lane 'row'
        float d2  = s1r + s2 - 2.0f * acc[j];
        d2 = fmaxf(d2, 0.0f);
        float dist = sqrtf(d2);
        float x    = fmaf(dist, av, bv);
        float e    = __expf(-x);
        float sg   = 1.0f / (1.0f + e);
        sg = fminf(sg, 1.0f);
        sg = fmaxf(sg, 1e-8f);
        po[row * 16 + m] = sg;                  // 16-lane groups = 64B segments
    }
}

extern "C" void kernel_launch(void* const* d_in, const int* in_sizes, int n_in,
                              void* d_out, int out_size, void* d_ws, size_t ws_size,
                              hipStream_t stream) {
    const float* z1 = (const float*)d_in[0];
    const float* z2 = (const float*)d_in[1];
    const float* pa = (const float*)d_in[2];
    const float* pb = (const float*)d_in[3];
    float* out      = (float*)d_out;

    dim3 grid(Bn / WPB);     // 8192 blocks
    dim3 block(THREADS);
    hipLaunchKernelGGL(get_logit_mc_kernel, grid, block, 0, stream,
                       z1, z2, pa, pb, out);
}